// Round 10
// baseline (135.637 us; speedup 1.0000x reference)
//
#include <hip/hip_runtime.h>
#include <math.h>

// AtomQueryFieldNet: NQ=4096, NA=512, pair MLP 18->64->64->32->1, cutoff mask,
// per-query 3-vector reduction, 3->64->3 head.
//
// R10: 4-tile interleave + X-fragment precompute.
//  - R5..R9 trend: no pipe >40% busy; wins came from shortening/widening the
//    per-wave serial chain. So: (1) 64 pairs per step (4 MFMA tiles) -> each
//    LDS write->read sync covers 2x work; (2) the rbf/exp X build moves to
//    compaction time (xbuf[CAP][32] f16, exact once per pair) -> hot loop
//    fetches X with one ds_read_b128 per tile instead of ~50 VALU.
//  - Transposed MFMA chain (R9): h^T = W^T @ X^T; lane holds 4 contiguous
//    hidden units of its own pair -> b64 packed exchange writes.
//  - repack pre-kernel (R9): fragment-ordered weights, 24 dwordx4 preload.
//  - fp16 in / fp32 accum; absmax 0.015625 (4.5x under threshold).

typedef _Float16 f16x8 __attribute__((ext_vector_type(8)));
typedef _Float16 f16x4 __attribute__((ext_vector_type(4)));
typedef float    f32x4 __attribute__((ext_vector_type(4)));

#define CAP 352   // max in-range atoms/query (center mean 268, sigma ~11 -> +7.4s)
#define XP2 72    // exchange row pitch in f16 (144B rows; b64/b128 aligned)
#define NT  4     // tiles (16 pairs each) per step

// ---- repack: weights -> MFMA fragment order in d_ws (see R9) ----
__global__ __launch_bounds__(64) void repack_kernel(
    const float* __restrict__ W1, const float* __restrict__ b1,
    const float* __restrict__ W2, const float* __restrict__ b2,
    const float* __restrict__ W3, const float* __restrict__ b3,
    const float* __restrict__ W4, char* __restrict__ ws)
{
    const int b = blockIdx.x, l = threadIdx.x;
    const int col = l & 15, quad = l >> 4;
    if (b < 16) {
        f16x8 v;
        #pragma unroll
        for (int j = 0; j < 8; ++j) {
            const int k = quad*8 + j;
            float x;
            if (b < 4) {
                const int mt = b;
                x = (k < 18) ? W1[k*64 + mt*16 + col]
                             : (k == 18 ? b1[mt*16 + col] : 0.0f);
            } else if (b < 12) {
                const int kc = (b-4) >> 2, mt = (b-4) & 3;
                x = W2[(kc*32 + k)*64 + mt*16 + col];
            } else {
                const int kc = (b-12) >> 1, mt = (b-12) & 1;
                x = W3[(kc*32 + k)*32 + mt*16 + col];
            }
            v[j] = (_Float16)x;
        }
        *(f16x8*)(ws + (b*64 + l)*16) = v;
    } else {
        const int d = b - 16;
        float o[4];
        #pragma unroll
        for (int rr = 0; rr < 4; ++rr) {
            const int idx = quad*4 + rr;
            if (d < 4)      o[rr] = b2[d*16 + idx];
            else if (d < 6) o[rr] = b3[(d-4)*16 + idx];
            else            o[rr] = W4[(d-6)*16 + idx];
        }
        *(float4*)(ws + 16384 + (d*64 + l)*16) = make_float4(o[0],o[1],o[2],o[3]);
    }
}

__global__ __launch_bounds__(64, 1) void aqfn_kernel(
    const float* __restrict__ atom_pos,   // (512,3)
    const float* __restrict__ atom_feat,  // (512,2)
    const float* __restrict__ query_pos,  // (4096,3)
    const float* __restrict__ b4,         // (1)
    const float* __restrict__ W5, const float* __restrict__ b5,  // (3,64),(64)
    const float* __restrict__ W6, const float* __restrict__ b6,  // (64,3),(3)
    const char*  __restrict__ ws,         // repacked weights
    float* __restrict__ out)              // (4096,3)
{
    __shared__ __align__(16) float4   rbuf[CAP];          // (rx,ry,rz,dist)
    __shared__ __align__(16) _Float16 xbuf[CAP][32];      // X fragments (f16)
    __shared__ __align__(16) _Float16 exch[NT][16*XP2];   // exchange buffers

    const int lane = threadIdx.x & 63;
    const int col  = lane & 15;
    const int quad = lane >> 4;
    const int q    = blockIdx.x;

    // ---- fragment preload: 24 coalesced dwordx4 loads ----
    const f16x8*  wsf = (const f16x8*)ws;
    const float4* wsb = (const float4*)(ws + 16384);
    f16x8 w1f[4], w2f[2][4], w3f[2][2];
    #pragma unroll
    for (int mt = 0; mt < 4; ++mt) w1f[mt] = wsf[mt*64 + lane];
    #pragma unroll
    for (int kc = 0; kc < 2; ++kc)
        #pragma unroll
        for (int mt = 0; mt < 4; ++mt) w2f[kc][mt] = wsf[(4 + kc*4 + mt)*64 + lane];
    #pragma unroll
    for (int kc = 0; kc < 2; ++kc)
        #pragma unroll
        for (int mt = 0; mt < 2; ++mt) w3f[kc][mt] = wsf[(12 + kc*2 + mt)*64 + lane];
    float4 b2v[4], b3v[2], w4v[2];
    #pragma unroll
    for (int mt = 0; mt < 4; ++mt) b2v[mt] = wsb[mt*64 + lane];
    #pragma unroll
    for (int mt = 0; mt < 2; ++mt) { b3v[mt] = wsb[(4+mt)*64 + lane];
                                     w4v[mt] = wsb[(6+mt)*64 + lane]; }
    const float b4v = b4[0];

    const float qx = query_pos[q*3+0];
    const float qy = query_pos[q*3+1];
    const float qz = query_pos[q*3+2];

    // ---- compaction + X-fragment build (once per in-range atom) ----
    int count = 0;
    #pragma unroll 1
    for (int it = 0; it < 8; ++it) {
        const int a = it*64 + lane;
        const float rx = qx - atom_pos[a*3+0];
        const float ry = qy - atom_pos[a*3+1];
        const float rz = qz - atom_pos[a*3+2];
        const float ex = __fadd_rn(rx, 1e-12f);
        const float ey = __fadd_rn(ry, 1e-12f);
        const float ez = __fadd_rn(rz, 1e-12f);
        const float dd = __fadd_rn(__fadd_rn(__fmul_rn(ex,ex), __fmul_rn(ey,ey)),
                                   __fmul_rn(ez,ez));
        const float dist = sqrtf(dd);
        const bool  in   = (dist <= 6.0f);
        const unsigned long long m = __ballot(in);
        const int p = count + (int)__popcll(m & ((1ull << lane) - 1ull));
        if (in && p < CAP) {
            rbuf[p] = make_float4(rx, ry, rz, dist);
            const float f0 = atom_feat[a*2+0];
            const float f1 = atom_feat[a*2+1];
            f16x8 xv[4];
            #pragma unroll
            for (int j = 0; j < 32; ++j) {
                float v;
                if (j == 0)       v = f0;
                else if (j == 1)  v = f1;
                else if (j < 18) {
                    const float tt = dist - 0.4f * (float)(j - 2); // centers linspace(0,6,16)
                    v = __expf(-10.0f * tt * tt);
                }
                else if (j == 18) v = 1.0f;    // bias slot (b1 folded into W1)
                else              v = 0.0f;
                xv[j >> 3][j & 7] = (_Float16)v;
            }
            #pragma unroll
            for (int c4 = 0; c4 < 4; ++c4)
                *(f16x8*)&xbuf[p][c4*8] = xv[c4];
        }
        count += (int)__popcll(m);
    }
    if (count > CAP) count = CAP;   // unreachable

    float wacc0 = 0.f, wacc1 = 0.f, wacc2 = 0.f;
    const int nsteps = (count + (NT*16 - 1)) / (NT*16);

    #pragma unroll 1
    for (int step = 0; step < nsteps; ++step) {
        const int row0 = step * (NT*16);

        int pr[NT];
        f16x8 xa[NT];
        #pragma unroll
        for (int u = 0; u < NT; ++u) {
            int p2 = row0 + u*16 + col;
            if (p2 >= count) p2 = count - 1;
            pr[u] = p2;
            xa[u] = *(const f16x8*)&xbuf[p2][quad*8];   // B-frag: X[pair][quad*8+j]
        }

        // ---- L1 transposed: h1^T[mt*16+quad*4+rr][pair=col] ----
        #pragma unroll
        for (int u = 0; u < NT; ++u)
            #pragma unroll
            for (int mt = 0; mt < 4; ++mt) {
                f32x4 c = {0.f, 0.f, 0.f, 0.f};
                c = __builtin_amdgcn_mfma_f32_16x16x32_f16(w1f[mt], xa[u], c, 0, 0, 0);
                f16x4 pk = {(_Float16)fmaxf(c[0],0.f), (_Float16)fmaxf(c[1],0.f),
                            (_Float16)fmaxf(c[2],0.f), (_Float16)fmaxf(c[3],0.f)};
                *(f16x4*)&exch[u][col*XP2 + mt*16 + quad*4] = pk;
            }
        f16x8 a2[NT][2];
        #pragma unroll
        for (int u = 0; u < NT; ++u)
            #pragma unroll
            for (int kc = 0; kc < 2; ++kc)
                a2[u][kc] = *(const f16x8*)&exch[u][col*XP2 + kc*32 + quad*8];

        // ---- L2 transposed ----
        #pragma unroll
        for (int u = 0; u < NT; ++u)
            #pragma unroll
            for (int mt = 0; mt < 4; ++mt) {
                f32x4 c = {b2v[mt].x, b2v[mt].y, b2v[mt].z, b2v[mt].w};
                c = __builtin_amdgcn_mfma_f32_16x16x32_f16(w2f[0][mt], a2[u][0], c, 0, 0, 0);
                c = __builtin_amdgcn_mfma_f32_16x16x32_f16(w2f[1][mt], a2[u][1], c, 0, 0, 0);
                f16x4 pk = {(_Float16)fmaxf(c[0],0.f), (_Float16)fmaxf(c[1],0.f),
                            (_Float16)fmaxf(c[2],0.f), (_Float16)fmaxf(c[3],0.f)};
                *(f16x4*)&exch[u][col*XP2 + mt*16 + quad*4] = pk;
            }
        f16x8 a3[NT][2];
        #pragma unroll
        for (int u = 0; u < NT; ++u)
            #pragma unroll
            for (int kc = 0; kc < 2; ++kc)
                a3[u][kc] = *(const f16x8*)&exch[u][col*XP2 + kc*32 + quad*8];

        // ---- L3 transposed + L4 partial + quad-reduce + fused accumulation ----
        #pragma unroll
        for (int u = 0; u < NT; ++u) {
            float s = 0.f;
            #pragma unroll
            for (int mt = 0; mt < 2; ++mt) {
                f32x4 c = {b3v[mt].x, b3v[mt].y, b3v[mt].z, b3v[mt].w};
                c = __builtin_amdgcn_mfma_f32_16x16x32_f16(w3f[0][mt], a3[u][0], c, 0, 0, 0);
                c = __builtin_amdgcn_mfma_f32_16x16x32_f16(w3f[1][mt], a3[u][1], c, 0, 0, 0);
                const float* wv = &w4v[mt].x;
                #pragma unroll
                for (int rr = 0; rr < 4; ++rr)
                    s = fmaf(fmaxf(c[rr], 0.f), wv[rr], s);
            }
            s += __shfl_xor(s, 16);
            s += __shfl_xor(s, 32);
            s += b4v;
            const bool  vld = (row0 + u*16 + col) < count;
            const float4 rv = rbuf[pr[u]];
            const float inv = __builtin_amdgcn_rcpf(rv.w + 1e-12f);
            const float wm  = vld ? (s * inv) : 0.f;
            wacc0 = fmaf(wm, rv.x, wacc0);
            wacc1 = fmaf(wm, rv.y, wacc1);
            wacc2 = fmaf(wm, rv.z, wacc2);
        }
    }

    // ---- 64-lane butterfly; each pair accumulated by all 4 quads -> x0.25 ----
    #pragma unroll
    for (int off = 1; off < 64; off <<= 1) {
        wacc0 += __shfl_xor(wacc0, off);
        wacc1 += __shfl_xor(wacc1, off);
        wacc2 += __shfl_xor(wacc2, off);
    }
    wacc0 *= 0.25f; wacc1 *= 0.25f; wacc2 *= 0.25f;

    // ---- head: 3 -> 64 -> 3 (lane = hidden unit) ----
    float th = fmaf(wacc0, W5[lane],
               fmaf(wacc1, W5[64+lane],
               fmaf(wacc2, W5[128+lane], b5[lane])));
    th = fmaxf(th, 0.f);
    float o0 = th * W6[lane*3+0];
    float o1 = th * W6[lane*3+1];
    float o2 = th * W6[lane*3+2];
    #pragma unroll
    for (int off = 1; off < 64; off <<= 1) {
        o0 += __shfl_xor(o0, off);
        o1 += __shfl_xor(o1, off);
        o2 += __shfl_xor(o2, off);
    }
    if (lane == 0) {
        out[q*3+0] = o0 + b6[0];
        out[q*3+1] = o1 + b6[1];
        out[q*3+2] = o2 + b6[2];
    }
}

extern "C" void kernel_launch(void* const* d_in, const int* in_sizes, int n_in,
                              void* d_out, int out_size, void* d_ws, size_t ws_size,
                              hipStream_t stream) {
    const float* atom_pos  = (const float*)d_in[0];
    const float* atom_feat = (const float*)d_in[1];
    const float* query_pos = (const float*)d_in[2];
    const float* W1 = (const float*)d_in[3];  const float* b1 = (const float*)d_in[4];
    const float* W2 = (const float*)d_in[5];  const float* b2 = (const float*)d_in[6];
    const float* W3 = (const float*)d_in[7];  const float* b3 = (const float*)d_in[8];
    const float* W4 = (const float*)d_in[9];  const float* b4 = (const float*)d_in[10];
    const float* W5 = (const float*)d_in[11]; const float* b5 = (const float*)d_in[12];
    const float* W6 = (const float*)d_in[13]; const float* b6 = (const float*)d_in[14];
    float* out = (float*)d_out;
    char*  ws  = (char*)d_ws;   // 16KB frags + 8KB biases

    hipLaunchKernelGGL(repack_kernel, dim3(24), dim3(64), 0, stream,
                       W1, b1, W2, b2, W3, b3, W4, ws);
    hipLaunchKernelGGL(aqfn_kernel, dim3(4096), dim3(64), 0, stream,
                       atom_pos, atom_feat, query_pos, b4, W5, b5, W6, b6,
                       (const char*)ws, out);
}

// Round 11
// 123.334 us; speedup vs baseline: 1.0998x; 1.0998x over previous
//
#include <hip/hip_runtime.h>
#include <math.h>

// AtomQueryFieldNet: NQ=4096, NA=512, pair MLP 18->64->64->32->1, cutoff mask,
// per-query 3-vector reduction, 3->64->3 head.
//
// R11: block = query (256 thr, 4 waves); wave = 128-atom segment.
//  - Measured invariant R8-R10: ~5 BLOCKS/CU resident regardless of size.
//    4-wave blocks -> ~20 waves/CU instead of ~5 (R9) -> latency holes filled.
//  - Each wave: ballot-compact its own segment (count<=128), then the exact
//    R9 hot loop (NT=2 interleave, transposed MFMA h^T=W^T X^T, in-loop exp
//    X-build, per-wave exchange). One __syncthreads + 4-vector LDS sum + head.
//  - LDS 28.7KB -> 5 blocks/CU cap = observed equilibrium. R10's mistake
//    (37KB xbuf, 1-wave blocks -> occ 8.7%) reverted.
//  - repack pre-kernel (R9): fragment-ordered weights, 24 dwordx4 preload.
//  - fp16 in / fp32 accum; absmax ~0.0156 (accumulation order differs only).

typedef _Float16 f16x8 __attribute__((ext_vector_type(8)));
typedef _Float16 f16x4 __attribute__((ext_vector_type(4)));
typedef _Float16 f16x2 __attribute__((ext_vector_type(2)));
typedef float    f32x4 __attribute__((ext_vector_type(4)));

#define XP2 72    // exchange row pitch in f16 (144B rows; b64/b128 aligned)
#define NT  2     // tiles (16 pairs) interleaved per step

// ---- repack: weights -> MFMA fragment order in d_ws (see R9) ----
__global__ __launch_bounds__(64) void repack_kernel(
    const float* __restrict__ W1, const float* __restrict__ b1,
    const float* __restrict__ W2, const float* __restrict__ b2,
    const float* __restrict__ W3, const float* __restrict__ b3,
    const float* __restrict__ W4, char* __restrict__ ws)
{
    const int b = blockIdx.x, l = threadIdx.x;
    const int col = l & 15, quad = l >> 4;
    if (b < 16) {
        f16x8 v;
        #pragma unroll
        for (int j = 0; j < 8; ++j) {
            const int k = quad*8 + j;
            float x;
            if (b < 4) {
                const int mt = b;
                x = (k < 18) ? W1[k*64 + mt*16 + col]
                             : (k == 18 ? b1[mt*16 + col] : 0.0f);
            } else if (b < 12) {
                const int kc = (b-4) >> 2, mt = (b-4) & 3;
                x = W2[(kc*32 + k)*64 + mt*16 + col];
            } else {
                const int kc = (b-12) >> 1, mt = (b-12) & 1;
                x = W3[(kc*32 + k)*32 + mt*16 + col];
            }
            v[j] = (_Float16)x;
        }
        *(f16x8*)(ws + (b*64 + l)*16) = v;
    } else {
        const int d = b - 16;
        float o[4];
        #pragma unroll
        for (int rr = 0; rr < 4; ++rr) {
            const int idx = quad*4 + rr;
            if (d < 4)      o[rr] = b2[d*16 + idx];
            else if (d < 6) o[rr] = b3[(d-4)*16 + idx];
            else            o[rr] = W4[(d-6)*16 + idx];
        }
        *(float4*)(ws + 16384 + (d*64 + l)*16) = make_float4(o[0],o[1],o[2],o[3]);
    }
}

__global__ __launch_bounds__(256, 1) void aqfn_kernel(
    const float* __restrict__ atom_pos,   // (512,3)
    const float* __restrict__ atom_feat,  // (512,2)
    const float* __restrict__ query_pos,  // (4096,3)
    const float* __restrict__ b4,         // (1)
    const float* __restrict__ W5, const float* __restrict__ b5,  // (3,64),(64)
    const float* __restrict__ W6, const float* __restrict__ b6,  // (64,3),(3)
    const char*  __restrict__ ws,         // repacked weights
    float* __restrict__ out)              // (4096,3)
{
    __shared__ __align__(16) float4   rbuf[4][128];         // per-wave segment
    __shared__ __align__(16) f16x2    fbuf[4][128];
    __shared__ __align__(16) _Float16 exch[4][NT][16*XP2];  // per-wave exchange
    __shared__ float wred[4][3];

    const int tid  = threadIdx.x;
    const int wave = __builtin_amdgcn_readfirstlane(tid >> 6);
    const int lane = tid & 63;
    const int col  = lane & 15;
    const int quad = lane >> 4;
    const int q    = blockIdx.x;

    // ---- fragment preload: 24 coalesced dwordx4 loads (per wave) ----
    const f16x8*  wsf = (const f16x8*)ws;
    const float4* wsb = (const float4*)(ws + 16384);
    f16x8 w1f[4], w2f[2][4], w3f[2][2];
    #pragma unroll
    for (int mt = 0; mt < 4; ++mt) w1f[mt] = wsf[mt*64 + lane];
    #pragma unroll
    for (int kc = 0; kc < 2; ++kc)
        #pragma unroll
        for (int mt = 0; mt < 4; ++mt) w2f[kc][mt] = wsf[(4 + kc*4 + mt)*64 + lane];
    #pragma unroll
    for (int kc = 0; kc < 2; ++kc)
        #pragma unroll
        for (int mt = 0; mt < 2; ++mt) w3f[kc][mt] = wsf[(12 + kc*2 + mt)*64 + lane];
    float4 b2v[4], b3v[2], w4v[2];
    #pragma unroll
    for (int mt = 0; mt < 4; ++mt) b2v[mt] = wsb[mt*64 + lane];
    #pragma unroll
    for (int mt = 0; mt < 2; ++mt) { b3v[mt] = wsb[(4+mt)*64 + lane];
                                     w4v[mt] = wsb[(6+mt)*64 + lane]; }
    const float b4v = b4[0];

    const float qx = query_pos[q*3+0];
    const float qy = query_pos[q*3+1];
    const float qz = query_pos[q*3+2];

    // ---- per-wave ballot compaction over segment [wave*128, +128) ----
    int count = 0;
    #pragma unroll 1
    for (int it = 0; it < 2; ++it) {
        const int a = wave*128 + it*64 + lane;
        const float rx = qx - atom_pos[a*3+0];
        const float ry = qy - atom_pos[a*3+1];
        const float rz = qz - atom_pos[a*3+2];
        const float ex = __fadd_rn(rx, 1e-12f);
        const float ey = __fadd_rn(ry, 1e-12f);
        const float ez = __fadd_rn(rz, 1e-12f);
        const float dd = __fadd_rn(__fadd_rn(__fmul_rn(ex,ex), __fmul_rn(ey,ey)),
                                   __fmul_rn(ez,ez));
        const float dist = sqrtf(dd);
        const bool  in   = (dist <= 6.0f);
        const unsigned long long m = __ballot(in);
        const int p = count + (int)__popcll(m & ((1ull << lane) - 1ull));
        if (in) {
            rbuf[wave][p] = make_float4(rx, ry, rz, dist);
            fbuf[wave][p] = f16x2{(_Float16)atom_feat[a*2+0], (_Float16)atom_feat[a*2+1]};
        }
        count += (int)__popcll(m);
    }

    float wacc0 = 0.f, wacc1 = 0.f, wacc2 = 0.f;
    const int nsteps = (count + (NT*16 - 1)) / (NT*16);

    #pragma unroll 1
    for (int step = 0; step < nsteps; ++step) {
        const int row0 = step * (NT*16);

        float4 rv[NT]; f16x2 ffv[NT];
        #pragma unroll
        for (int u = 0; u < NT; ++u) {
            int pr = row0 + u*16 + col;
            if (pr >= count) pr = count - 1;
            rv[u]  = rbuf[wave][pr];
            ffv[u] = fbuf[wave][pr];
        }

        // X B-frags: B[k=quad*8+j][n=col]; x = [f0,f1,rbf(16),1(bias),0...]
        f16x8 xa[NT];
        #pragma unroll
        for (int u = 0; u < NT; ++u) {
            const float dist = rv[u].w;
            #pragma unroll
            for (int j = 0; j < 8; ++j) {
                const int k = quad*8 + j;
                const float tt = dist - 0.4f * (float)(k - 2);  // centers linspace(0,6,16)
                float v = __expf(-10.0f * tt * tt);
                v = (k < 18) ? v : 0.0f;
                _Float16 xv = (_Float16)v;
                if (k == 18) xv = (_Float16)1.0f;      // bias slot (b1 in W1)
                if (j == 0) xv = (quad == 0) ? ffv[u][0] : xv;
                if (j == 1) xv = (quad == 0) ? ffv[u][1] : xv;
                xa[u][j] = xv;
            }
        }

        // ---- L1 transposed: h1^T[mt*16+quad*4+rr][pair=col] ----
        #pragma unroll
        for (int u = 0; u < NT; ++u)
            #pragma unroll
            for (int mt = 0; mt < 4; ++mt) {
                f32x4 c = {0.f, 0.f, 0.f, 0.f};
                c = __builtin_amdgcn_mfma_f32_16x16x32_f16(w1f[mt], xa[u], c, 0, 0, 0);
                f16x4 pk = {(_Float16)fmaxf(c[0],0.f), (_Float16)fmaxf(c[1],0.f),
                            (_Float16)fmaxf(c[2],0.f), (_Float16)fmaxf(c[3],0.f)};
                *(f16x4*)&exch[wave][u][col*XP2 + mt*16 + quad*4] = pk;
            }
        f16x8 a2[NT][2];
        #pragma unroll
        for (int u = 0; u < NT; ++u)
            #pragma unroll
            for (int kc = 0; kc < 2; ++kc)
                a2[u][kc] = *(const f16x8*)&exch[wave][u][col*XP2 + kc*32 + quad*8];

        // ---- L2 transposed ----
        #pragma unroll
        for (int u = 0; u < NT; ++u)
            #pragma unroll
            for (int mt = 0; mt < 4; ++mt) {
                f32x4 c = {b2v[mt].x, b2v[mt].y, b2v[mt].z, b2v[mt].w};
                c = __builtin_amdgcn_mfma_f32_16x16x32_f16(w2f[0][mt], a2[u][0], c, 0, 0, 0);
                c = __builtin_amdgcn_mfma_f32_16x16x32_f16(w2f[1][mt], a2[u][1], c, 0, 0, 0);
                f16x4 pk = {(_Float16)fmaxf(c[0],0.f), (_Float16)fmaxf(c[1],0.f),
                            (_Float16)fmaxf(c[2],0.f), (_Float16)fmaxf(c[3],0.f)};
                *(f16x4*)&exch[wave][u][col*XP2 + mt*16 + quad*4] = pk;
            }
        f16x8 a3[NT][2];
        #pragma unroll
        for (int u = 0; u < NT; ++u)
            #pragma unroll
            for (int kc = 0; kc < 2; ++kc)
                a3[u][kc] = *(const f16x8*)&exch[wave][u][col*XP2 + kc*32 + quad*8];

        // ---- L3 transposed + L4 partial + quad-reduce + fused accumulation ----
        #pragma unroll
        for (int u = 0; u < NT; ++u) {
            float s = 0.f;
            #pragma unroll
            for (int mt = 0; mt < 2; ++mt) {
                f32x4 c = {b3v[mt].x, b3v[mt].y, b3v[mt].z, b3v[mt].w};
                c = __builtin_amdgcn_mfma_f32_16x16x32_f16(w3f[0][mt], a3[u][0], c, 0, 0, 0);
                c = __builtin_amdgcn_mfma_f32_16x16x32_f16(w3f[1][mt], a3[u][1], c, 0, 0, 0);
                const float* wv = &w4v[mt].x;
                #pragma unroll
                for (int rr = 0; rr < 4; ++rr)
                    s = fmaf(fmaxf(c[rr], 0.f), wv[rr], s);
            }
            s += __shfl_xor(s, 16);
            s += __shfl_xor(s, 32);
            s += b4v;
            const int  p2  = row0 + u*16 + col;
            const bool vld = (p2 < count);
            const float inv = __builtin_amdgcn_rcpf(rv[u].w + 1e-12f);
            const float wm  = vld ? (s * inv) : 0.f;
            wacc0 = fmaf(wm, rv[u].x, wacc0);
            wacc1 = fmaf(wm, rv[u].y, wacc1);
            wacc2 = fmaf(wm, rv[u].z, wacc2);
        }
    }

    // ---- 64-lane butterfly; each pair counted by 4 quads -> x0.25 ----
    #pragma unroll
    for (int off = 1; off < 64; off <<= 1) {
        wacc0 += __shfl_xor(wacc0, off);
        wacc1 += __shfl_xor(wacc1, off);
        wacc2 += __shfl_xor(wacc2, off);
    }
    if (lane == 0) {
        wred[wave][0] = wacc0 * 0.25f;
        wred[wave][1] = wacc1 * 0.25f;
        wred[wave][2] = wacc2 * 0.25f;
    }
    __syncthreads();

    // ---- head: 3 -> 64 -> 3 (wave 0, lane = hidden unit) ----
    if (wave == 0) {
        const float v0 = wred[0][0] + wred[1][0] + wred[2][0] + wred[3][0];
        const float v1 = wred[0][1] + wred[1][1] + wred[2][1] + wred[3][1];
        const float v2 = wred[0][2] + wred[1][2] + wred[2][2] + wred[3][2];
        float th = fmaf(v0, W5[lane],
                   fmaf(v1, W5[64+lane],
                   fmaf(v2, W5[128+lane], b5[lane])));
        th = fmaxf(th, 0.f);
        float o0 = th * W6[lane*3+0];
        float o1 = th * W6[lane*3+1];
        float o2 = th * W6[lane*3+2];
        #pragma unroll
        for (int off = 1; off < 64; off <<= 1) {
            o0 += __shfl_xor(o0, off);
            o1 += __shfl_xor(o1, off);
            o2 += __shfl_xor(o2, off);
        }
        if (lane == 0) {
            out[q*3+0] = o0 + b6[0];
            out[q*3+1] = o1 + b6[1];
            out[q*3+2] = o2 + b6[2];
        }
    }
}

extern "C" void kernel_launch(void* const* d_in, const int* in_sizes, int n_in,
                              void* d_out, int out_size, void* d_ws, size_t ws_size,
                              hipStream_t stream) {
    const float* atom_pos  = (const float*)d_in[0];
    const float* atom_feat = (const float*)d_in[1];
    const float* query_pos = (const float*)d_in[2];
    const float* W1 = (const float*)d_in[3];  const float* b1 = (const float*)d_in[4];
    const float* W2 = (const float*)d_in[5];  const float* b2 = (const float*)d_in[6];
    const float* W3 = (const float*)d_in[7];  const float* b3 = (const float*)d_in[8];
    const float* W4 = (const float*)d_in[9];  const float* b4 = (const float*)d_in[10];
    const float* W5 = (const float*)d_in[11]; const float* b5 = (const float*)d_in[12];
    const float* W6 = (const float*)d_in[13]; const float* b6 = (const float*)d_in[14];
    float* out = (float*)d_out;
    char*  ws  = (char*)d_ws;   // 16KB frags + 8KB biases

    hipLaunchKernelGGL(repack_kernel, dim3(24), dim3(64), 0, stream,
                       W1, b1, W2, b2, W3, b3, W4, ws);
    hipLaunchKernelGGL(aqfn_kernel, dim3(4096), dim3(256), 0, stream,
                       atom_pos, atom_feat, query_pos, b4, W5, b5, W6, b6,
                       (const char*)ws, out);
}

// Round 12
// 118.735 us; speedup vs baseline: 1.1424x; 1.0387x over previous
//
#include <hip/hip_runtime.h>
#include <math.h>

// AtomQueryFieldNet: NQ=4096, NA=512, pair MLP 18->64->64->32->1, cutoff mask,
// per-query 3-vector reduction, 3->64->3 head.
//
// R12: R11 residency + R9 work-efficiency.
//  - R11 (block=query, 4 waves, per-wave segments) fixed occupancy (VALUBusy
//    38->53%) but padded 57%: count_w~45 per segment vs 32-pair step quantum.
//  - R12: block-level SHARED compacted list (two-pass deterministic: per-wave
//    ballot counts -> 4-entry LDS scan -> prefix writes; 2 barriers), then
//    waves take 32-pair chunks round-robin (chunk = wave, wave+4, ...).
//    Slots: ~280 -> ceil(count/32)*32 ~ 192 (7% padding) = ~30% less MLP work.
//  - Hot loop byte-identical to R11 (transposed MFMA, NT=2, per-wave exchange).
//  - repack pre-kernel (R9): fragment-ordered weights, 24 dwordx4 preload.
//  - fp16 in / fp32 accum; absmax ~0.0156.

typedef _Float16 f16x8 __attribute__((ext_vector_type(8)));
typedef _Float16 f16x4 __attribute__((ext_vector_type(4)));
typedef _Float16 f16x2 __attribute__((ext_vector_type(2)));
typedef float    f32x4 __attribute__((ext_vector_type(4)));

#define CAP 352   // max in-range atoms/query (geometric max ~270)
#define XP2 72    // exchange row pitch in f16 (144B rows; b64/b128 aligned)
#define NT  2     // tiles (16 pairs) interleaved per chunk

// ---- repack: weights -> MFMA fragment order in d_ws (see R9) ----
__global__ __launch_bounds__(64) void repack_kernel(
    const float* __restrict__ W1, const float* __restrict__ b1,
    const float* __restrict__ W2, const float* __restrict__ b2,
    const float* __restrict__ W3, const float* __restrict__ b3,
    const float* __restrict__ W4, char* __restrict__ ws)
{
    const int b = blockIdx.x, l = threadIdx.x;
    const int col = l & 15, quad = l >> 4;
    if (b < 16) {
        f16x8 v;
        #pragma unroll
        for (int j = 0; j < 8; ++j) {
            const int k = quad*8 + j;
            float x;
            if (b < 4) {
                const int mt = b;
                x = (k < 18) ? W1[k*64 + mt*16 + col]
                             : (k == 18 ? b1[mt*16 + col] : 0.0f);
            } else if (b < 12) {
                const int kc = (b-4) >> 2, mt = (b-4) & 3;
                x = W2[(kc*32 + k)*64 + mt*16 + col];
            } else {
                const int kc = (b-12) >> 1, mt = (b-12) & 1;
                x = W3[(kc*32 + k)*32 + mt*16 + col];
            }
            v[j] = (_Float16)x;
        }
        *(f16x8*)(ws + (b*64 + l)*16) = v;
    } else {
        const int d = b - 16;
        float o[4];
        #pragma unroll
        for (int rr = 0; rr < 4; ++rr) {
            const int idx = quad*4 + rr;
            if (d < 4)      o[rr] = b2[d*16 + idx];
            else if (d < 6) o[rr] = b3[(d-4)*16 + idx];
            else            o[rr] = W4[(d-6)*16 + idx];
        }
        *(float4*)(ws + 16384 + (d*64 + l)*16) = make_float4(o[0],o[1],o[2],o[3]);
    }
}

__global__ __launch_bounds__(256, 1) void aqfn_kernel(
    const float* __restrict__ atom_pos,   // (512,3)
    const float* __restrict__ atom_feat,  // (512,2)
    const float* __restrict__ query_pos,  // (4096,3)
    const float* __restrict__ b4,         // (1)
    const float* __restrict__ W5, const float* __restrict__ b5,  // (3,64),(64)
    const float* __restrict__ W6, const float* __restrict__ b6,  // (64,3),(3)
    const char*  __restrict__ ws,         // repacked weights
    float* __restrict__ out)              // (4096,3)
{
    __shared__ __align__(16) float4   rbuf[CAP];            // shared compacted list
    __shared__ __align__(16) f16x2    fbuf[CAP];
    __shared__ __align__(16) _Float16 exch[4][NT][16*XP2];  // per-wave exchange
    __shared__ float wred[4][3];
    __shared__ int   wcnt[4];

    const int tid  = threadIdx.x;
    const int wave = __builtin_amdgcn_readfirstlane(tid >> 6);
    const int lane = tid & 63;
    const int col  = lane & 15;
    const int quad = lane >> 4;
    const int q    = blockIdx.x;

    // ---- fragment preload: 24 coalesced dwordx4 loads (per wave) ----
    const f16x8*  wsf = (const f16x8*)ws;
    const float4* wsb = (const float4*)(ws + 16384);
    f16x8 w1f[4], w2f[2][4], w3f[2][2];
    #pragma unroll
    for (int mt = 0; mt < 4; ++mt) w1f[mt] = wsf[mt*64 + lane];
    #pragma unroll
    for (int kc = 0; kc < 2; ++kc)
        #pragma unroll
        for (int mt = 0; mt < 4; ++mt) w2f[kc][mt] = wsf[(4 + kc*4 + mt)*64 + lane];
    #pragma unroll
    for (int kc = 0; kc < 2; ++kc)
        #pragma unroll
        for (int mt = 0; mt < 2; ++mt) w3f[kc][mt] = wsf[(12 + kc*2 + mt)*64 + lane];
    float4 b2v[4], b3v[2], w4v[2];
    #pragma unroll
    for (int mt = 0; mt < 4; ++mt) b2v[mt] = wsb[mt*64 + lane];
    #pragma unroll
    for (int mt = 0; mt < 2; ++mt) { b3v[mt] = wsb[(4+mt)*64 + lane];
                                     w4v[mt] = wsb[(6+mt)*64 + lane]; }
    const float b4v = b4[0];

    const float qx = query_pos[q*3+0];
    const float qy = query_pos[q*3+1];
    const float qz = query_pos[q*3+2];

    // ---- pass 1: per-wave ballots over segment [wave*128, +128), keep data ----
    float rxv[2], ryv[2], rzv[2], dv[2], f0v[2], f1v[2];
    unsigned long long msk[2];
    int mycnt = 0;
    #pragma unroll
    for (int it = 0; it < 2; ++it) {
        const int a = wave*128 + it*64 + lane;
        const float rx = qx - atom_pos[a*3+0];
        const float ry = qy - atom_pos[a*3+1];
        const float rz = qz - atom_pos[a*3+2];
        const float ex = __fadd_rn(rx, 1e-12f);
        const float ey = __fadd_rn(ry, 1e-12f);
        const float ez = __fadd_rn(rz, 1e-12f);
        const float dd = __fadd_rn(__fadd_rn(__fmul_rn(ex,ex), __fmul_rn(ey,ey)),
                                   __fmul_rn(ez,ez));
        const float dist = sqrtf(dd);
        rxv[it] = rx; ryv[it] = ry; rzv[it] = rz; dv[it] = dist;
        f0v[it] = atom_feat[a*2+0]; f1v[it] = atom_feat[a*2+1];
        msk[it] = __ballot(dist <= 6.0f);
        mycnt  += (int)__popcll(msk[it]);
    }
    if (lane == 0) wcnt[wave] = mycnt;
    __syncthreads();

    // exclusive prefix over 4 wave counts
    int base = 0, count = 0;
    #pragma unroll
    for (int w = 0; w < 4; ++w) {
        const int c = wcnt[w];
        if (w < wave) base += c;
        count += c;
    }
    if (count > CAP) count = CAP;

    // ---- pass 2: prefix-offset writes into the shared list ----
    {
        int off0 = base;
        #pragma unroll
        for (int it = 0; it < 2; ++it) {
            const bool in = (msk[it] >> lane) & 1ull;
            const int  p  = off0 + (int)__popcll(msk[it] & ((1ull << lane) - 1ull));
            if (in && p < CAP) {
                rbuf[p] = make_float4(rxv[it], ryv[it], rzv[it], dv[it]);
                fbuf[p] = f16x2{(_Float16)f0v[it], (_Float16)f1v[it]};
            }
            off0 += (int)__popcll(msk[it]);
        }
    }
    __syncthreads();

    // ---- MLP over shared list: 32-pair chunks round-robin across waves ----
    float wacc0 = 0.f, wacc1 = 0.f, wacc2 = 0.f;
    const int nchunks = (count + (NT*16 - 1)) / (NT*16);

    #pragma unroll 1
    for (int chunk = wave; chunk < nchunks; chunk += 4) {
        const int row0 = chunk * (NT*16);

        float4 rv[NT]; f16x2 ffv[NT];
        #pragma unroll
        for (int u = 0; u < NT; ++u) {
            int pr = row0 + u*16 + col;
            if (pr >= count) pr = count - 1;
            rv[u]  = rbuf[pr];
            ffv[u] = fbuf[pr];
        }

        // X B-frags: B[k=quad*8+j][n=col]; x = [f0,f1,rbf(16),1(bias),0...]
        f16x8 xa[NT];
        #pragma unroll
        for (int u = 0; u < NT; ++u) {
            const float dist = rv[u].w;
            #pragma unroll
            for (int j = 0; j < 8; ++j) {
                const int k = quad*8 + j;
                const float tt = dist - 0.4f * (float)(k - 2);  // centers linspace(0,6,16)
                float v = __expf(-10.0f * tt * tt);
                v = (k < 18) ? v : 0.0f;
                _Float16 xv = (_Float16)v;
                if (k == 18) xv = (_Float16)1.0f;      // bias slot (b1 in W1)
                if (j == 0) xv = (quad == 0) ? ffv[u][0] : xv;
                if (j == 1) xv = (quad == 0) ? ffv[u][1] : xv;
                xa[u][j] = xv;
            }
        }

        // ---- L1 transposed: h1^T[mt*16+quad*4+rr][pair=col] ----
        #pragma unroll
        for (int u = 0; u < NT; ++u)
            #pragma unroll
            for (int mt = 0; mt < 4; ++mt) {
                f32x4 c = {0.f, 0.f, 0.f, 0.f};
                c = __builtin_amdgcn_mfma_f32_16x16x32_f16(w1f[mt], xa[u], c, 0, 0, 0);
                f16x4 pk = {(_Float16)fmaxf(c[0],0.f), (_Float16)fmaxf(c[1],0.f),
                            (_Float16)fmaxf(c[2],0.f), (_Float16)fmaxf(c[3],0.f)};
                *(f16x4*)&exch[wave][u][col*XP2 + mt*16 + quad*4] = pk;
            }
        f16x8 a2[NT][2];
        #pragma unroll
        for (int u = 0; u < NT; ++u)
            #pragma unroll
            for (int kc = 0; kc < 2; ++kc)
                a2[u][kc] = *(const f16x8*)&exch[wave][u][col*XP2 + kc*32 + quad*8];

        // ---- L2 transposed ----
        #pragma unroll
        for (int u = 0; u < NT; ++u)
            #pragma unroll
            for (int mt = 0; mt < 4; ++mt) {
                f32x4 c = {b2v[mt].x, b2v[mt].y, b2v[mt].z, b2v[mt].w};
                c = __builtin_amdgcn_mfma_f32_16x16x32_f16(w2f[0][mt], a2[u][0], c, 0, 0, 0);
                c = __builtin_amdgcn_mfma_f32_16x16x32_f16(w2f[1][mt], a2[u][1], c, 0, 0, 0);
                f16x4 pk = {(_Float16)fmaxf(c[0],0.f), (_Float16)fmaxf(c[1],0.f),
                            (_Float16)fmaxf(c[2],0.f), (_Float16)fmaxf(c[3],0.f)};
                *(f16x4*)&exch[wave][u][col*XP2 + mt*16 + quad*4] = pk;
            }
        f16x8 a3[NT][2];
        #pragma unroll
        for (int u = 0; u < NT; ++u)
            #pragma unroll
            for (int kc = 0; kc < 2; ++kc)
                a3[u][kc] = *(const f16x8*)&exch[wave][u][col*XP2 + kc*32 + quad*8];

        // ---- L3 transposed + L4 partial + quad-reduce + fused accumulation ----
        #pragma unroll
        for (int u = 0; u < NT; ++u) {
            float s = 0.f;
            #pragma unroll
            for (int mt = 0; mt < 2; ++mt) {
                f32x4 c = {b3v[mt].x, b3v[mt].y, b3v[mt].z, b3v[mt].w};
                c = __builtin_amdgcn_mfma_f32_16x16x32_f16(w3f[0][mt], a3[u][0], c, 0, 0, 0);
                c = __builtin_amdgcn_mfma_f32_16x16x32_f16(w3f[1][mt], a3[u][1], c, 0, 0, 0);
                const float* wv = &w4v[mt].x;
                #pragma unroll
                for (int rr = 0; rr < 4; ++rr)
                    s = fmaf(fmaxf(c[rr], 0.f), wv[rr], s);
            }
            s += __shfl_xor(s, 16);
            s += __shfl_xor(s, 32);
            s += b4v;
            const int  p2  = row0 + u*16 + col;
            const bool vld = (p2 < count);
            const float inv = __builtin_amdgcn_rcpf(rv[u].w + 1e-12f);
            const float wm  = vld ? (s * inv) : 0.f;
            wacc0 = fmaf(wm, rv[u].x, wacc0);
            wacc1 = fmaf(wm, rv[u].y, wacc1);
            wacc2 = fmaf(wm, rv[u].z, wacc2);
        }
    }

    // ---- 64-lane butterfly; each pair counted by 4 quads -> x0.25 ----
    #pragma unroll
    for (int off = 1; off < 64; off <<= 1) {
        wacc0 += __shfl_xor(wacc0, off);
        wacc1 += __shfl_xor(wacc1, off);
        wacc2 += __shfl_xor(wacc2, off);
    }
    if (lane == 0) {
        wred[wave][0] = wacc0 * 0.25f;
        wred[wave][1] = wacc1 * 0.25f;
        wred[wave][2] = wacc2 * 0.25f;
    }
    __syncthreads();

    // ---- head: 3 -> 64 -> 3 (wave 0, lane = hidden unit) ----
    if (wave == 0) {
        const float v0 = wred[0][0] + wred[1][0] + wred[2][0] + wred[3][0];
        const float v1 = wred[0][1] + wred[1][1] + wred[2][1] + wred[3][1];
        const float v2 = wred[0][2] + wred[1][2] + wred[2][2] + wred[3][2];
        float th = fmaf(v0, W5[lane],
                   fmaf(v1, W5[64+lane],
                   fmaf(v2, W5[128+lane], b5[lane])));
        th = fmaxf(th, 0.f);
        float o0 = th * W6[lane*3+0];
        float o1 = th * W6[lane*3+1];
        float o2 = th * W6[lane*3+2];
        #pragma unroll
        for (int off = 1; off < 64; off <<= 1) {
            o0 += __shfl_xor(o0, off);
            o1 += __shfl_xor(o1, off);
            o2 += __shfl_xor(o2, off);
        }
        if (lane == 0) {
            out[q*3+0] = o0 + b6[0];
            out[q*3+1] = o1 + b6[1];
            out[q*3+2] = o2 + b6[2];
        }
    }
}

extern "C" void kernel_launch(void* const* d_in, const int* in_sizes, int n_in,
                              void* d_out, int out_size, void* d_ws, size_t ws_size,
                              hipStream_t stream) {
    const float* atom_pos  = (const float*)d_in[0];
    const float* atom_feat = (const float*)d_in[1];
    const float* query_pos = (const float*)d_in[2];
    const float* W1 = (const float*)d_in[3];  const float* b1 = (const float*)d_in[4];
    const float* W2 = (const float*)d_in[5];  const float* b2 = (const float*)d_in[6];
    const float* W3 = (const float*)d_in[7];  const float* b3 = (const float*)d_in[8];
    const float* W4 = (const float*)d_in[9];  const float* b4 = (const float*)d_in[10];
    const float* W5 = (const float*)d_in[11]; const float* b5 = (const float*)d_in[12];
    const float* W6 = (const float*)d_in[13]; const float* b6 = (const float*)d_in[14];
    float* out = (float*)d_out;
    char*  ws  = (char*)d_ws;   // 16KB frags + 8KB biases

    hipLaunchKernelGGL(repack_kernel, dim3(24), dim3(64), 0, stream,
                       W1, b1, W2, b2, W3, b3, W4, ws);
    hipLaunchKernelGGL(aqfn_kernel, dim3(4096), dim3(256), 0, stream,
                       atom_pos, atom_feat, query_pos, b4, W5, b5, W6, b6,
                       (const char*)ws, out);
}